// Round 3
// baseline (369.127 us; speedup 1.0000x reference)
//
#include <hip/hip_runtime.h>

#define MAXLEN 100
#define HDIM 64
#define HSTR 72   // ushorts per h-stage row: 144 B, 16B-aligned -> ds_read_b128

typedef __attribute__((ext_vector_type(8))) short bf16x8;
typedef __attribute__((ext_vector_type(4))) float f32x4;

__device__ __forceinline__ unsigned short f2bf_u(float f) {   // RNE f32->bf16
    unsigned u = __float_as_uint(f);
    u += 0x7fffu + ((u >> 16) & 1u);
    return (unsigned short)(u >> 16);
}
__device__ __forceinline__ unsigned pk2(float a, float b) {
    return (unsigned)f2bf_u(a) | ((unsigned)f2bf_u(b) << 16);
}
__device__ __forceinline__ bf16x8 pack8(f32x4 a, f32x4 b) {
    union { unsigned u[4]; bf16x8 v; } c;
    c.u[0] = pk2(a[0], a[1]); c.u[1] = pk2(a[2], a[3]);
    c.u[2] = pk2(b[0], b[1]); c.u[3] = pk2(b[2], b[3]);
    return c.v;
}
__device__ __forceinline__ float fsig(float v) {
    return __fdividef(1.0f, 1.0f + __expf(-v));
}
__device__ __forceinline__ float ftanh(float v) {
    return __fdividef(2.0f, 1.0f + __expf(-2.0f * v)) - 1.0f;
}

// --- per-segment start/len via binary search (index sorted) ---
__global__ void seg_bounds_kernel(const int* __restrict__ index, int N, int B,
                                  int* __restrict__ starts, int* __restrict__ lens) {
    int b = blockIdx.x * blockDim.x + threadIdx.x;
    if (b >= B) return;
    int lo = 0, hi = N;
    while (lo < hi) { int mid = (lo + hi) >> 1; if (index[mid] < b) lo = mid + 1; else hi = mid; }
    int s = lo;
    hi = N;
    while (lo < hi) { int mid = (lo + hi) >> 1; if (index[mid] < b + 1) lo = mid + 1; else hi = mid; }
    int len = lo - s;
    starts[b] = s;
    lens[b] = len < MAXLEN ? len : MAXLEN;
}

// --- counting sort of segment ids by length (lengths in [0,MAXLEN]) ---
// Blocks then process 16 near-equal-length segments -> minimal lmax waste.
__global__ void seg_sort_kernel(const int* __restrict__ lens, int B,
                                int* __restrict__ order) {
    __shared__ int hcnt[MAXLEN + 1];
    __shared__ int hbase[MAXLEN + 1];
    const int tid = threadIdx.x;
    for (int i = tid; i <= MAXLEN; i += blockDim.x) hcnt[i] = 0;
    __syncthreads();
    for (int i = tid; i < B; i += blockDim.x) atomicAdd(&hcnt[lens[i]], 1);
    __syncthreads();
    if (tid == 0) {
        int acc = 0;
        for (int i = 0; i <= MAXLEN; ++i) { hbase[i] = acc; acc += hcnt[i]; }
    }
    __syncthreads();
    for (int i = tid; i < B; i += blockDim.x) {
        int pos = atomicAdd(&hbase[lens[i]], 1);
        order[pos] = i;
    }
}

// --- x fp32 -> bf16 row-major staging pass (memory-bound) ---
__global__ void xcast_kernel(const float* __restrict__ x,
                             unsigned short* __restrict__ xbf, long long n8) {
    long long i = (long long)blockIdx.x * blockDim.x + threadIdx.x;
    const long long stride = (long long)gridDim.x * blockDim.x;
    for (; i < n8; i += stride) {
        const f32x4* p = (const f32x4*)(x + i * 8);
        f32x4 a = p[0], b = p[1];
        uint4 o;
        o.x = pk2(a[0], a[1]); o.y = pk2(a[2], a[3]);
        o.z = pk2(b[0], b[1]); o.w = pk2(b[2], b[3]);
        *(uint4*)(xbf + i * 8) = o;
    }
}

// --- recurrent kernel: 16 segments/block, 4 waves, wave w owns hidden cols [16w,16w+16).
// All A-frag data arrives as ready-made bf16 (global xbf, LDS h) -> near-zero pack VALU.
template <bool PRE>
__global__ __launch_bounds__(256, 2)
void lstm_mfma_kernel(const float* __restrict__ x,
                      const unsigned short* __restrict__ xbf,
                      const float* __restrict__ Wih,
                      const float* __restrict__ Whh,
                      const float* __restrict__ bih,
                      const float* __restrict__ bhh,
                      const int* __restrict__ starts,
                      const int* __restrict__ lens,
                      const int* __restrict__ order,
                      float* __restrict__ out) {
    const int tid  = threadIdx.x;
    const int w    = tid >> 6;
    const int lane = tid & 63;
    const int l15  = lane & 15;
    const int quad = lane >> 4;
    const int segbase = blockIdx.x * 16;
    const int ncol = w * 16 + l15;

    __shared__ __align__(16) unsigned short hst[2][16][HSTR];

    // Weight B-fragments + fused-bias C fragments, register-resident.
    bf16x8 wi[4][2], wh[4][2];
    f32x4 bias4[4];
#pragma unroll
    for (int g = 0; g < 4; ++g) {
        const int row = g * HDIM + ncol;
        float bb = bih[row] + bhh[row];
        f32x4 b4 = {bb, bb, bb, bb};
        bias4[g] = b4;
#pragma unroll
        for (int kt = 0; kt < 2; ++kt) {
            const f32x4* pi = (const f32x4*)(Wih + (size_t)row * HDIM + kt * 32 + quad * 8);
            const f32x4* ph = (const f32x4*)(Whh + (size_t)row * HDIM + kt * 32 + quad * 8);
            wi[g][kt] = pack8(pi[0], pi[1]);
            wh[g][kt] = pack8(ph[0], ph[1]);
        }
    }

    // Segment metadata through the length-sorted order.
    const int sf      = order[segbase + l15];
    const int start_f = starts[sf];
    const int len_f   = lens[sf];
    int seg4[4], len4[4];
#pragma unroll
    for (int r = 0; r < 4; ++r) {
        seg4[r] = order[segbase + quad * 4 + r];
        len4[r] = lens[seg4[r]];
    }
    int lmax = len_f;
#pragma unroll
    for (int d = 1; d < 16; d <<= 1) {
        int o = __shfl_xor(lmax, d);
        lmax = o > lmax ? o : lmax;
    }

    // Zero both h-stage buffers.
    for (int i = tid; i < 2 * 16 * HSTR / 2; i += 256) ((int*)hst)[i] = 0;

    const unsigned short* xb = xbf + (size_t)start_f * HDIM + quad * 8;
    const float* xf = x + (size_t)start_f * HDIM + quad * 8;

    bf16x8 xa0 = {0,0,0,0,0,0,0,0}, xa1 = xa0, xn0 = xa0, xn1 = xa0;
    if (len_f > 0) {
        if (PRE) {
            xa0 = *(const bf16x8*)(xb);
            xa1 = *(const bf16x8*)(xb + 32);
        } else {
            const f32x4* p = (const f32x4*)xf;
            xa0 = pack8(p[0], p[1]);
            const f32x4* q = (const f32x4*)(xf + 32);
            xa1 = pack8(q[0], q[1]);
        }
    }
    f32x4 nx0a, nx0b, nx1a, nx1b;   // fp32 fallback prefetch regs

    float c4[4] = {0, 0, 0, 0}, h4[4] = {0, 0, 0, 0};
    __syncthreads();

    for (int t = 0; t < lmax; ++t) {
        // Prefetch x row t+1 (lands during MFMA + gate math + barrier).
        const bool pf = (t + 1 < len_f);
        if (PRE) {
            if (pf) {
                const unsigned short* p = xb + (size_t)(t + 1) * HDIM;
                xn0 = *(const bf16x8*)(p);
                xn1 = *(const bf16x8*)(p + 32);
            }
        } else {
            if (pf) {
                const f32x4* p = (const f32x4*)(xf + (size_t)(t + 1) * HDIM);
                nx0a = p[0]; nx0b = p[1]; nx1a = p[2]; nx1b = p[3];
            }
        }

        // h A-fragments: direct 16B LDS reads, no repack.
        const unsigned short* hr = &hst[t & 1][l15][quad * 8];
        bf16x8 ha0 = *(const bf16x8*)(hr);
        bf16x8 ha1 = *(const bf16x8*)(hr + 32);

        f32x4 acc[4];
#pragma unroll
        for (int g = 0; g < 4; ++g) {
            f32x4 a = __builtin_amdgcn_mfma_f32_16x16x32_bf16(xa0, wi[g][0], bias4[g], 0, 0, 0);
            a = __builtin_amdgcn_mfma_f32_16x16x32_bf16(xa1, wi[g][1], a, 0, 0, 0);
            a = __builtin_amdgcn_mfma_f32_16x16x32_bf16(ha0, wh[g][0], a, 0, 0, 0);
            a = __builtin_amdgcn_mfma_f32_16x16x32_bf16(ha1, wh[g][1], a, 0, 0, 0);
            acc[g] = a;
        }

        unsigned short* hw = &hst[(t + 1) & 1][quad * 4][ncol];
#pragma unroll
        for (int r = 0; r < 4; ++r) {
            float gi = fsig(acc[0][r]);
            float gf = fsig(acc[1][r]);
            float gg = ftanh(acc[2][r]);
            float go = fsig(acc[3][r]);
            float cn = gf * c4[r] + gi * gg;
            float hn = go * ftanh(cn);
            if (t < len4[r]) { c4[r] = cn; h4[r] = hn; }
            hw[r * HSTR] = f2bf_u(h4[r]);
        }
        __syncthreads();

        if (pf) {
            if (PRE) { xa0 = xn0; xa1 = xn1; }
            else     { xa0 = pack8(nx0a, nx0b); xa1 = pack8(nx1a, nx1b); }
        }
    }

#pragma unroll
    for (int r = 0; r < 4; ++r)
        out[(size_t)seg4[r] * HDIM + ncol] = h4[r];
}

extern "C" void kernel_launch(void* const* d_in, const int* in_sizes, int n_in,
                              void* d_out, int out_size, void* d_ws, size_t ws_size,
                              hipStream_t stream) {
    const float* x     = (const float*)d_in[0];
    const float* Wih   = (const float*)d_in[1];
    const float* Whh   = (const float*)d_in[2];
    const float* bih   = (const float*)d_in[3];
    const float* bhh   = (const float*)d_in[4];
    const int*   index = (const int*)d_in[5];

    const int N = in_sizes[5];
    const int B = out_size / HDIM;   // 8192

    int* starts = (int*)d_ws;
    int* lens   = starts + B;
    int* order  = lens + B;
    const size_t off = ((size_t)3 * B * 4 + 255) & ~(size_t)255;
    unsigned short* xbf = (unsigned short*)((char*)d_ws + off);
    const bool pre = ws_size >= off + (size_t)N * HDIM * 2;

    seg_bounds_kernel<<<(B + 255) / 256, 256, 0, stream>>>(index, N, B, starts, lens);
    seg_sort_kernel<<<1, 256, 0, stream>>>(lens, B, order);

    const int nblocks = (B + 15) / 16;
    if (pre) {
        xcast_kernel<<<2048, 256, 0, stream>>>(x, xbf, (long long)N * (HDIM / 8));
        lstm_mfma_kernel<true><<<nblocks, 256, 0, stream>>>(x, xbf, Wih, Whh, bih, bhh,
                                                            starts, lens, order, (float*)d_out);
    } else {
        lstm_mfma_kernel<false><<<nblocks, 256, 0, stream>>>(x, xbf, Wih, Whh, bih, bhh,
                                                             starts, lens, order, (float*)d_out);
    }
}